// Round 1
// baseline (477.319 us; speedup 1.0000x reference)
//
#include <hip/hip_runtime.h>
#include <stdint.h>

typedef unsigned short u16;
typedef __attribute__((ext_vector_type(8))) short short8;
typedef __attribute__((ext_vector_type(4))) float f32x4;

__device__ __forceinline__ u16 f2bf(float f){
  union { float f; uint32_t u; } v; v.f = f;
  uint32_t u = v.u;
  uint32_t r = (u + 0x7FFFu + ((u >> 16) & 1u)) >> 16;
  return (u16)r;
}
__device__ __forceinline__ float bf2f(u16 h){
  union { uint32_t u; float f; } v; v.u = ((uint32_t)h) << 16;
  return v.f;
}
__device__ __forceinline__ f32x4 mfma16(short8 a, short8 b, f32x4 c){
  return __builtin_amdgcn_mfma_f32_16x16x32_bf16(a, b, c, 0, 0, 0);
}
__device__ __forceinline__ void gl_lds16(const u16* g, u16* l){
  __builtin_amdgcn_global_load_lds((const __attribute__((address_space(1))) void*)g,
                                   (__attribute__((address_space(3))) void*)l, 16, 0, 0);
}

// ---------------- f32 -> bf16 convert (x) ----------------
__global__ __launch_bounds__(256) void cvt_x(const float* __restrict__ s,
                                             u16* __restrict__ d, int n4){
  const int i = blockIdx.x*256 + threadIdx.x;
  if (i >= n4) return;
  const float4 v = ((const float4*)s)[i];
  ushort4 pk;
  pk.x = f2bf(v.x); pk.y = f2bf(v.y); pk.z = f2bf(v.z); pk.w = f2bf(v.w);
  ((ushort4*)d)[i] = pk;
}

// ---------------- f32 [R][C] -> bf16 [C][R] transpose ----------------
__global__ __launch_bounds__(256) void transpose_cvt(const float* __restrict__ src,
    u16* __restrict__ dst, int R, int C)
{
  __shared__ float tile[32][33];
  const int tx = threadIdx.x, ty = threadIdx.y;
  const int c0 = blockIdx.x << 5, r0 = blockIdx.y << 5;
  #pragma unroll
  for (int i=0;i<4;i++)
    tile[ty + (i<<3)][tx] = src[(size_t)(r0 + ty + (i<<3))*C + c0 + tx];
  __syncthreads();
  #pragma unroll
  for (int i=0;i<4;i++)
    dst[(size_t)(c0 + ty + (i<<3))*R + r0 + tx] = f2bf(tile[tx][ty + (i<<3)]);
}

// ---------------- V transpose: qkv v-slice [S][128] -> vT [128][S] per (b,kv) ----------------
__global__ __launch_bounds__(256) void v_transpose(const u16* __restrict__ qkv,
    u16* __restrict__ vT)
{
  __shared__ u16 tile[32][33];
  const int tx = threadIdx.x, ty = threadIdx.y;
  const int s0 = blockIdx.x << 5, d0 = blockIdx.y << 5;
  const int bk = blockIdx.z; const int b = bk >> 2, kv = bk & 3;
  const u16* src = qkv + (size_t)b*2048*3072 + 2560 + kv*128;
  #pragma unroll
  for (int i=0;i<4;i++)
    tile[ty + (i<<3)][tx] = src[(size_t)(s0 + ty + (i<<3))*3072 + d0 + tx];
  __syncthreads();
  u16* dst = vT + (size_t)((b<<2)+kv)*128*2048;
  #pragma unroll
  for (int i=0;i<4;i++)
    dst[(size_t)(d0 + ty + (i<<3))*2048 + s0 + tx] = tile[tx][ty + (i<<3)];
}

// ---------------- RMSNorm over each 128-wide head row of q and k ----------------
__global__ __launch_bounds__(256) void rmsnorm_qk(u16* __restrict__ qkv,
    const float* __restrict__ qw, const float* __restrict__ kw)
{
  const int lane = threadIdx.x & 63;
  const int rid = blockIdx.x*4 + (threadIdx.x >> 6);   // 0..81919
  const int row = rid / 20;
  const int slot = rid % 20;                            // 0..15 q heads, 16..19 k heads
  u16* p = qkv + (size_t)row*3072 + slot*128 + (lane<<1);
  const u16 r0 = p[0], r1 = p[1];
  const float a = bf2f(r0), c = bf2f(r1);
  float ss = a*a + c*c;
  #pragma unroll
  for (int off=1; off<64; off<<=1) ss += __shfl_xor(ss, off);
  const float sc = rsqrtf(ss*(1.0f/128.0f) + 1e-6f);
  const float* wp = (slot < 16) ? qw : kw;
  const float w0 = wp[lane<<1], w1 = wp[(lane<<1)+1];
  p[0] = f2bf(a*sc*w0);
  p[1] = f2bf(c*sc*w1);
}

// ---------------- bf16 GEMM: A[M][K] @ BT[N][K]^T -> C[M][ldc] ----------------
// 128x128 tile, BK=64, 4 waves (2x2), global_load_lds w/ pre-swizzled source,
// XOR-swizzled LDS reads (T2).
template<int CBF16>
__global__ __launch_bounds__(256) void gemm_bt(const u16* __restrict__ A,
    const u16* __restrict__ BT, void* __restrict__ Cp,
    int M, int N, int K, int ldc)
{
  __shared__ u16 As[128*64];
  __shared__ u16 Bs[128*64];
  const int tid = threadIdx.x;
  const int w = tid >> 6, lane = tid & 63;
  const int l15 = lane & 15, lg = lane >> 4;
  const int nbx = N >> 7;
  const int nwg = gridDim.x;
  int bid = blockIdx.x;
  bid = (bid & 7) * (nwg >> 3) + (bid >> 3);   // bijective XCD swizzle (nwg % 8 == 0)
  const int m0 = (bid / nbx) << 7;
  const int n0 = (bid % nbx) << 7;
  const int wm = w >> 1, wn = w & 1;

  f32x4 acc[4][4];
  #pragma unroll
  for (int m=0;m<4;m++)
    #pragma unroll
    for (int n=0;n<4;n++) acc[m][n] = (f32x4){0.f,0.f,0.f,0.f};

  const int rowi = lane >> 3;                 // 0..7 row-within-instr
  const int colS = ((lane & 7) ^ rowi) << 3;  // pre-swizzled source col (elems)

  for (int k0 = 0; k0 < K; k0 += 64) {
    #pragma unroll
    for (int jj=0;jj<4;jj++){
      const int j = (w<<2) + jj;              // 0..15
      const int row = (j<<3) + rowi;          // 0..127
      gl_lds16(A  + (size_t)(m0+row)*K + k0 + colS, As + j*512);
      gl_lds16(BT + (size_t)(n0+row)*K + k0 + colS, Bs + j*512);
    }
    __syncthreads();
    short8 af[4][2], bf[4][2];
    #pragma unroll
    for (int m=0;m<4;m++){
      const int row = (wm<<6) + (m<<4) + l15;
      #pragma unroll
      for (int kk=0;kk<2;kk++){
        const int kb = (kk<<6) + (lg<<4);
        af[m][kk] = *(const short8*)((const char*)As + row*128 + (kb ^ ((row&7)<<4)));
      }
    }
    #pragma unroll
    for (int n=0;n<4;n++){
      const int row = (wn<<6) + (n<<4) + l15;
      #pragma unroll
      for (int kk=0;kk<2;kk++){
        const int kb = (kk<<6) + (lg<<4);
        bf[n][kk] = *(const short8*)((const char*)Bs + row*128 + (kb ^ ((row&7)<<4)));
      }
    }
    #pragma unroll
    for (int kk=0;kk<2;kk++)
      #pragma unroll
      for (int m=0;m<4;m++)
        #pragma unroll
        for (int n=0;n<4;n++)
          acc[m][n] = mfma16(af[m][kk], bf[n][kk], acc[m][n]);
    __syncthreads();
  }

  #pragma unroll
  for (int m=0;m<4;m++){
    #pragma unroll
    for (int n=0;n<4;n++){
      const int col = n0 + (wn<<6) + (n<<4) + l15;
      #pragma unroll
      for (int r=0;r<4;r++){
        const int row = m0 + (wm<<6) + (m<<4) + (lg<<2) + r;
        if (CBF16) ((u16*)Cp)[(size_t)row*ldc + col] = f2bf(acc[m][n][r]);
        else       ((float*)Cp)[(size_t)row*ldc + col] = acc[m][n][r];
      }
    }
  }
}

// ---------------- causal GQA flash attention ----------------
// grid (32 qblk, 16 h, 2 b), 4 waves; each wave owns 16 q rows.
// Q in regs; K [64][128] + V^T [128][64] staged via swizzled global_load_lds;
// online softmax; P through per-wave swizzled LDS into MFMA A-layout.
__global__ __launch_bounds__(256) void attn_kernel(const u16* __restrict__ qkv,
    const u16* __restrict__ vT, u16* __restrict__ aout)
{
  __shared__ u16 Klds[64*128];
  __shared__ u16 Vlds[128*64];
  __shared__ u16 Plds[4*16*64];
  const int tid = threadIdx.x;
  const int w = tid >> 6, lane = tid & 63;
  const int l15 = lane & 15, lg = lane >> 4;
  const int qb = (int)gridDim.x - 1 - (int)blockIdx.x;  // big blocks dispatch first
  const int h = blockIdx.y, b = blockIdx.z;
  const int kvh = h >> 2;
  const int q0 = qb << 6;
  const float SCALE = 0.08838834764831845f;  // 1/sqrt(128)

  const u16* qkvb = qkv + (size_t)b*2048*3072;
  short8 qf[4];
  {
    const u16* qp = qkvb + (size_t)(q0 + (w<<4) + l15)*3072 + h*128 + lg*8;
    #pragma unroll
    for (int kk=0;kk<4;kk++) qf[kk] = *(const short8*)(qp + kk*32);
  }
  f32x4 oacc[8];
  #pragma unroll
  for (int d=0;d<8;d++) oacc[d] = (f32x4){0.f,0.f,0.f,0.f};
  float m_run[4], lsum[4];
  #pragma unroll
  for (int r=0;r<4;r++){ m_run[r] = -__builtin_inff(); lsum[r] = 0.f; }

  const u16* kb_ = qkvb + 2048 + kvh*128;
  const u16* vb_ = vT + (size_t)((b<<2)+kvh)*128*2048;

  for (int t=0; t<=qb; ++t){
    const int t0 = t << 6;
    #pragma unroll
    for (int jj=0;jj<4;jj++){
      const int j = (w<<2) + jj;               // 0..15
      const int rK = (j<<2) + lg;              // 0..63
      const int cK = ((l15 ^ (rK & 15)) << 3);
      gl_lds16(kb_ + (size_t)(t0 + rK)*3072 + cK, Klds + j*512);
      const int rV = (j<<3) + (lane>>3);       // 0..127
      const int cV = (((lane&7) ^ (lane>>3)) << 3);
      gl_lds16(vb_ + (size_t)rV*2048 + t0 + cV, Vlds + j*512);
    }
    __syncthreads();

    // S = Q K^T
    f32x4 sacc[4];
    #pragma unroll
    for (int nf=0;nf<4;nf++) sacc[nf] = (f32x4){0.f,0.f,0.f,0.f};
    #pragma unroll
    for (int kk=0;kk<4;kk++){
      const int kbyte = (kk<<6) + (lg<<4);
      #pragma unroll
      for (int nf=0;nf<4;nf++){
        const int row = (nf<<4) + l15;
        const short8 kv8 = *(const short8*)((const char*)Klds + row*256 + (kbyte ^ ((row&15)<<4)));
        sacc[nf] = mfma16(qf[kk], kv8, sacc[nf]);
      }
    }

    // online softmax (per reg-row r; rows replicated across 16 lanes)
    float pbuf[4][4];
    float corr[4];
    #pragma unroll
    for (int r=0;r<4;r++){
      const int rowg = q0 + (w<<4) + (lg<<2) + r;
      float mx = -__builtin_inff();
      #pragma unroll
      for (int nf=0;nf<4;nf++){
        float sv = sacc[nf][r] * SCALE;
        if (t == qb){
          const int colg = t0 + (nf<<4) + l15;
          if (colg > rowg) sv = -__builtin_inff();
        }
        pbuf[nf][r] = sv;
        mx = fmaxf(mx, sv);
      }
      mx = fmaxf(mx, __shfl_xor(mx, 1));
      mx = fmaxf(mx, __shfl_xor(mx, 2));
      mx = fmaxf(mx, __shfl_xor(mx, 4));
      mx = fmaxf(mx, __shfl_xor(mx, 8));
      const float mnew = fmaxf(m_run[r], mx);
      corr[r] = __expf(m_run[r] - mnew);
      m_run[r] = mnew;
      float rs = 0.f;
      #pragma unroll
      for (int nf=0;nf<4;nf++){
        const float p = __expf(pbuf[nf][r] - mnew);
        pbuf[nf][r] = p;
        rs += p;
      }
      rs += __shfl_xor(rs, 1);
      rs += __shfl_xor(rs, 2);
      rs += __shfl_xor(rs, 4);
      rs += __shfl_xor(rs, 8);
      lsum[r] = lsum[r]*corr[r] + rs;
    }

    // P -> per-wave LDS (swizzled), C-layout write / A-layout read
    #pragma unroll
    for (int nf=0;nf<4;nf++)
      #pragma unroll
      for (int r=0;r<4;r++){
        const int row = (lg<<2) + r;
        const int cb = ((nf<<4) + l15) << 1;
        *(u16*)((char*)Plds + (w<<11) + row*128 + (cb ^ ((row&7)<<4))) = f2bf(pbuf[nf][r]);
      }
    asm volatile("s_waitcnt lgkmcnt(0)" ::: "memory");
    __builtin_amdgcn_sched_barrier(0);

    #pragma unroll
    for (int d=0;d<8;d++)
      #pragma unroll
      for (int r=0;r<4;r++)
        oacc[d][r] *= corr[r];

    // O += P V
    #pragma unroll
    for (int kk=0;kk<2;kk++){
      const int kbyte = (kk<<6) + (lg<<4);
      const short8 pa = *(const short8*)((const char*)Plds + (w<<11) + l15*128 + (kbyte ^ ((l15&7)<<4)));
      #pragma unroll
      for (int d=0;d<8;d++){
        const int row = (d<<4) + l15;
        const short8 vv = *(const short8*)((const char*)Vlds + row*128 + (kbyte ^ ((row&7)<<4)));
        oacc[d] = mfma16(pa, vv, oacc[d]);
      }
    }
    __syncthreads();
  }

  #pragma unroll
  for (int r=0;r<4;r++){
    const float inv = 1.0f / lsum[r];
    u16* op = aout + (size_t)(b*2048 + q0 + (w<<4) + (lg<<2) + r)*2048 + h*128 + l15;
    #pragma unroll
    for (int d=0;d<8;d++)
      op[d<<4] = f2bf(oacc[d][r] * inv);
  }
}

extern "C" void kernel_launch(void* const* d_in, const int* in_sizes, int n_in,
                              void* d_out, int out_size, void* d_ws, size_t ws_size,
                              hipStream_t stream) {
  const float* x  = (const float*)d_in[0];
  const float* wq = (const float*)d_in[1];
  const float* wk = (const float*)d_in[2];
  const float* wv = (const float*)d_in[3];
  const float* wo = (const float*)d_in[4];
  const float* qw = (const float*)d_in[5];
  const float* kw = (const float*)d_in[6];
  char* ws = (char*)d_ws;
  u16* xbf   = (u16*)(ws);                 // 16 MB; reused as attn_out
  u16* wqkvT = (u16*)(ws + 16777216);      // 12 MB: [3072][2048] = wqT|wkT|wvT
  u16* woT   = (u16*)(ws + 29360128);      // 8 MB:  [2048][2048]
  u16* qkv   = (u16*)(ws + 37748736);      // 24 MB: [4096][3072] q|k|v
  u16* vT    = (u16*)(ws + 62914560);      // 4 MB:  [8][128][2048]
  float* out = (float*)d_out;

  dim3 tb(32,8);
  cvt_x<<<8192, 256, 0, stream>>>(x, xbf, 2097152);
  transpose_cvt<<<dim3(64,64), tb, 0, stream>>>(wq, wqkvT,             2048, 2048);
  transpose_cvt<<<dim3(16,64), tb, 0, stream>>>(wk, wqkvT + 2048*2048, 2048, 512);
  transpose_cvt<<<dim3(16,64), tb, 0, stream>>>(wv, wqkvT + 2560*2048, 2048, 512);
  transpose_cvt<<<dim3(64,64), tb, 0, stream>>>(wo, woT,               2048, 2048);
  gemm_bt<1><<<768, 256, 0, stream>>>(xbf, wqkvT, qkv, 4096, 3072, 2048, 3072);
  rmsnorm_qk<<<20480, 256, 0, stream>>>(qkv, qw, kw);
  v_transpose<<<dim3(64,4,8), tb, 0, stream>>>(qkv, vT);
  attn_kernel<<<dim3(32,16,2), 256, 0, stream>>>(qkv, vT, xbf);
  gemm_bt<0><<<512, 256, 0, stream>>>(xbf, woT, out, 4096, 2048, 2048, 2048);
}

// Round 2
// 254.338 us; speedup vs baseline: 1.8767x; 1.8767x over previous
//
#include <hip/hip_runtime.h>
#include <stdint.h>

typedef unsigned short u16;
typedef __attribute__((ext_vector_type(8))) short short8;
typedef __attribute__((ext_vector_type(4))) float f32x4;

__device__ __forceinline__ u16 f2bf(float f){
  union { float f; uint32_t u; } v; v.f = f;
  uint32_t u = v.u;
  uint32_t r = (u + 0x7FFFu + ((u >> 16) & 1u)) >> 16;
  return (u16)r;
}
__device__ __forceinline__ float bf2f(u16 h){
  union { uint32_t u; float f; } v; v.u = ((uint32_t)h) << 16;
  return v.f;
}
__device__ __forceinline__ f32x4 mfma16(short8 a, short8 b, f32x4 c){
  return __builtin_amdgcn_mfma_f32_16x16x32_bf16(a, b, c, 0, 0, 0);
}
__device__ __forceinline__ void gl_lds16(const u16* g, u16* l){
  __builtin_amdgcn_global_load_lds((const __attribute__((address_space(1))) void*)g,
                                   (__attribute__((address_space(3))) void*)l, 16, 0, 0);
}

// ---------------- f32 -> bf16 convert (x) ----------------
__global__ __launch_bounds__(256) void cvt_x(const float* __restrict__ s,
                                             u16* __restrict__ d, int n4){
  const int i = blockIdx.x*256 + threadIdx.x;
  if (i >= n4) return;
  const float4 v = ((const float4*)s)[i];
  ushort4 pk;
  pk.x = f2bf(v.x); pk.y = f2bf(v.y); pk.z = f2bf(v.z); pk.w = f2bf(v.w);
  ((ushort4*)d)[i] = pk;
}

// ---------------- f32 [R][C] -> bf16 [C][R] transpose ----------------
__global__ __launch_bounds__(256) void transpose_cvt(const float* __restrict__ src,
    u16* __restrict__ dst, int R, int C)
{
  __shared__ float tile[32][33];
  const int tx = threadIdx.x, ty = threadIdx.y;
  const int c0 = blockIdx.x << 5, r0 = blockIdx.y << 5;
  #pragma unroll
  for (int i=0;i<4;i++)
    tile[ty + (i<<3)][tx] = src[(size_t)(r0 + ty + (i<<3))*C + c0 + tx];
  __syncthreads();
  #pragma unroll
  for (int i=0;i<4;i++)
    dst[(size_t)(c0 + ty + (i<<3))*R + r0 + tx] = f2bf(tile[tx][ty + (i<<3)]);
}

// ---------------- V transpose: qkv v-slice [S][128] -> vT [128][S] per (b,kv) ----------------
__global__ __launch_bounds__(256) void v_transpose(const u16* __restrict__ qkv,
    u16* __restrict__ vT)
{
  __shared__ u16 tile[32][33];
  const int tx = threadIdx.x, ty = threadIdx.y;
  const int s0 = blockIdx.x << 5, d0 = blockIdx.y << 5;
  const int bk = blockIdx.z; const int b = bk >> 2, kv = bk & 3;
  const u16* src = qkv + (size_t)b*2048*3072 + 2560 + kv*128;
  #pragma unroll
  for (int i=0;i<4;i++)
    tile[ty + (i<<3)][tx] = src[(size_t)(s0 + ty + (i<<3))*3072 + d0 + tx];
  __syncthreads();
  u16* dst = vT + (size_t)((b<<2)+kv)*128*2048;
  #pragma unroll
  for (int i=0;i<4;i++)
    dst[(size_t)(d0 + ty + (i<<3))*2048 + s0 + tx] = tile[tx][ty + (i<<3)];
}

// ---------------- RMSNorm over each 128-wide head row of q and k ----------------
__global__ __launch_bounds__(256) void rmsnorm_qk(u16* __restrict__ qkv,
    const float* __restrict__ qw, const float* __restrict__ kw)
{
  const int lane = threadIdx.x & 63;
  const int rid = blockIdx.x*4 + (threadIdx.x >> 6);   // 0..81919
  const int row = rid / 20;
  const int slot = rid % 20;                            // 0..15 q heads, 16..19 k heads
  u16* p = qkv + (size_t)row*3072 + slot*128 + (lane<<1);
  const u16 r0 = p[0], r1 = p[1];
  const float a = bf2f(r0), c = bf2f(r1);
  float ss = a*a + c*c;
  #pragma unroll
  for (int off=1; off<64; off<<=1) ss += __shfl_xor(ss, off);
  const float sc = rsqrtf(ss*(1.0f/128.0f) + 1e-6f);
  const float* wp = (slot < 16) ? qw : kw;
  const float w0 = wp[lane<<1], w1 = wp[(lane<<1)+1];
  p[0] = f2bf(a*sc*w0);
  p[1] = f2bf(c*sc*w1);
}

// ---------------- bf16 GEMM: A[M][K] @ BT[N][K]^T -> C[M][ldc] ----------------
template<int CBF16>
__global__ __launch_bounds__(256) void gemm_bt(const u16* __restrict__ A,
    const u16* __restrict__ BT, void* __restrict__ Cp,
    int M, int N, int K, int ldc)
{
  __shared__ u16 As[128*64];
  __shared__ u16 Bs[128*64];
  const int tid = threadIdx.x;
  const int w = tid >> 6, lane = tid & 63;
  const int l15 = lane & 15, lg = lane >> 4;
  const int nbx = N >> 7;
  const int nwg = gridDim.x;
  int bid = blockIdx.x;
  bid = (bid & 7) * (nwg >> 3) + (bid >> 3);   // bijective XCD swizzle (nwg % 8 == 0)
  const int m0 = (bid / nbx) << 7;
  const int n0 = (bid % nbx) << 7;
  const int wm = w >> 1, wn = w & 1;

  f32x4 acc[4][4];
  #pragma unroll
  for (int m=0;m<4;m++)
    #pragma unroll
    for (int n=0;n<4;n++) acc[m][n] = (f32x4){0.f,0.f,0.f,0.f};

  const int rowi = lane >> 3;                 // 0..7 row-within-instr
  const int colS = ((lane & 7) ^ rowi) << 3;  // pre-swizzled source col (elems)

  for (int k0 = 0; k0 < K; k0 += 64) {
    #pragma unroll
    for (int jj=0;jj<4;jj++){
      const int j = (w<<2) + jj;              // 0..15
      const int row = (j<<3) + rowi;          // 0..127
      gl_lds16(A  + (size_t)(m0+row)*K + k0 + colS, As + j*512);
      gl_lds16(BT + (size_t)(n0+row)*K + k0 + colS, Bs + j*512);
    }
    __syncthreads();
    short8 af[4][2], bf[4][2];
    #pragma unroll
    for (int m=0;m<4;m++){
      const int row = (wm<<6) + (m<<4) + l15;
      #pragma unroll
      for (int kk=0;kk<2;kk++){
        const int kb = (kk<<6) + (lg<<4);
        af[m][kk] = *(const short8*)((const char*)As + row*128 + (kb ^ ((row&7)<<4)));
      }
    }
    #pragma unroll
    for (int n=0;n<4;n++){
      const int row = (wn<<6) + (n<<4) + l15;
      #pragma unroll
      for (int kk=0;kk<2;kk++){
        const int kb = (kk<<6) + (lg<<4);
        bf[n][kk] = *(const short8*)((const char*)Bs + row*128 + (kb ^ ((row&7)<<4)));
      }
    }
    #pragma unroll
    for (int kk=0;kk<2;kk++)
      #pragma unroll
      for (int m=0;m<4;m++)
        #pragma unroll
        for (int n=0;n<4;n++)
          acc[m][n] = mfma16(af[m][kk], bf[n][kk], acc[m][n]);
    __syncthreads();
  }

  #pragma unroll
  for (int m=0;m<4;m++){
    #pragma unroll
    for (int n=0;n<4;n++){
      const int col = n0 + (wn<<6) + (n<<4) + l15;
      #pragma unroll
      for (int r=0;r<4;r++){
        const int row = m0 + (wm<<6) + (m<<4) + (lg<<2) + r;
        if (CBF16) ((u16*)Cp)[(size_t)row*ldc + col] = f2bf(acc[m][n][r]);
        else       ((float*)Cp)[(size_t)row*ldc + col] = acc[m][n][r];
      }
    }
  }
}

// ---------------- per-tile attention compute: QK^T, online softmax, PV ----------------
__device__ __forceinline__ void attn_tile(
    const char* Kb, const char* Vb, char* Pw,
    const short8* qf, f32x4* oacc, float* m_run, float* lsum,
    int rowbase, int t0, bool diag, int l15, int lg)
{
  const float SCALE = 0.08838834764831845f;  // 1/sqrt(128)
  f32x4 sacc[4];
  #pragma unroll
  for (int nf=0;nf<4;nf++) sacc[nf] = (f32x4){0.f,0.f,0.f,0.f};
  #pragma unroll
  for (int kk=0;kk<4;kk++){
    const int kbyte = (kk<<6) + (lg<<4);
    #pragma unroll
    for (int nf=0;nf<4;nf++){
      const int row = (nf<<4) + l15;
      const short8 kv8 = *(const short8*)(Kb + row*256 + (kbyte ^ ((row&15)<<4)));
      sacc[nf] = mfma16(qf[kk], kv8, sacc[nf]);
    }
  }

  float pbuf[4][4], corr[4];
  #pragma unroll
  for (int r=0;r<4;r++){
    const int rowg = rowbase + (lg<<2) + r;
    float mx = -__builtin_inff();
    #pragma unroll
    for (int nf=0;nf<4;nf++){
      float sv = sacc[nf][r] * SCALE;
      if (diag){
        const int colg = t0 + (nf<<4) + l15;
        if (colg > rowg) sv = -__builtin_inff();
      }
      pbuf[nf][r] = sv;
      mx = fmaxf(mx, sv);
    }
    mx = fmaxf(mx, __shfl_xor(mx, 1));
    mx = fmaxf(mx, __shfl_xor(mx, 2));
    mx = fmaxf(mx, __shfl_xor(mx, 4));
    mx = fmaxf(mx, __shfl_xor(mx, 8));
    const float mnew = fmaxf(m_run[r], mx);
    corr[r] = __expf(m_run[r] - mnew);
    m_run[r] = mnew;
    float rs = 0.f;
    #pragma unroll
    for (int nf=0;nf<4;nf++){
      const float p = __expf(pbuf[nf][r] - mnew);
      pbuf[nf][r] = p;
      rs += p;
    }
    rs += __shfl_xor(rs, 1);
    rs += __shfl_xor(rs, 2);
    rs += __shfl_xor(rs, 4);
    rs += __shfl_xor(rs, 8);
    lsum[r] = lsum[r]*corr[r] + rs;
  }

  // P -> per-wave LDS (swizzled)
  #pragma unroll
  for (int nf=0;nf<4;nf++)
    #pragma unroll
    for (int r=0;r<4;r++){
      const int row = (lg<<2) + r;
      const int cb = ((nf<<4) + l15) << 1;
      *(u16*)(Pw + row*128 + (cb ^ ((row&7)<<4))) = f2bf(pbuf[nf][r]);
    }
  asm volatile("s_waitcnt lgkmcnt(0)" ::: "memory");
  __builtin_amdgcn_sched_barrier(0);

  #pragma unroll
  for (int d=0;d<8;d++)
    #pragma unroll
    for (int r=0;r<4;r++)
      oacc[d][r] *= corr[r];

  #pragma unroll
  for (int kk=0;kk<2;kk++){
    const int kbyte = (kk<<6) + (lg<<4);
    const short8 pa = *(const short8*)(Pw + l15*128 + (kbyte ^ ((l15&7)<<4)));
    #pragma unroll
    for (int d=0;d<8;d++){
      const int row = (d<<4) + l15;
      const short8 vv = *(const short8*)(Vb + row*128 + (kbyte ^ ((row&7)<<4)));
      oacc[d] = mfma16(pa, vv, oacc[d]);
    }
  }
}

// ---------------- causal GQA flash attention, triangle-paired + double-buffered ----------------
// grid (16 pair, 16 h, 2 b); block handles q-tiles p and 31-p (64 rows each),
// sharing each K/V tile load. K/V double-buffered in LDS, prefetch issued at
// loop top, one vmcnt(0)+barrier per iteration at loop bottom.
__global__ __launch_bounds__(256, 2) void attn_kernel(const u16* __restrict__ qkv,
    const u16* __restrict__ vT, u16* __restrict__ aout)
{
  __shared__ u16 Klds[2][64*128];
  __shared__ u16 Vlds[2][128*64];
  __shared__ u16 Plds[4*16*64];
  const int tid = threadIdx.x;
  const int w = tid >> 6, lane = tid & 63;
  const int l15 = lane & 15, lg = lane >> 4;
  const int p = blockIdx.x;                 // 0..15
  const int h = blockIdx.y, b = blockIdx.z;
  const int kvh = h >> 2;
  const int qlo = p, qhi = 31 - p;
  const int q0L = qlo << 6, q0H = qhi << 6;

  const u16* qkvb = qkv + (size_t)b*2048*3072;
  short8 qfL[4], qfH[4];
  {
    const u16* qpL = qkvb + (size_t)(q0L + (w<<4) + l15)*3072 + h*128 + lg*8;
    const u16* qpH = qkvb + (size_t)(q0H + (w<<4) + l15)*3072 + h*128 + lg*8;
    #pragma unroll
    for (int kk=0;kk<4;kk++){ qfL[kk] = *(const short8*)(qpL + kk*32);
                              qfH[kk] = *(const short8*)(qpH + kk*32); }
  }
  f32x4 oaccL[8], oaccH[8];
  #pragma unroll
  for (int d=0;d<8;d++){ oaccL[d] = (f32x4){0.f,0.f,0.f,0.f};
                         oaccH[d] = (f32x4){0.f,0.f,0.f,0.f}; }
  float mL[4], lL[4], mH[4], lH[4];
  #pragma unroll
  for (int r=0;r<4;r++){ mL[r] = -__builtin_inff(); lL[r] = 0.f;
                         mH[r] = -__builtin_inff(); lH[r] = 0.f; }

  const u16* kb_ = qkvb + 2048 + kvh*128;
  const u16* vb_ = vT + (size_t)((b<<2)+kvh)*128*2048;

#define STAGE(T, BUF) do { \
    const int t0s = (T) << 6; \
    _Pragma("unroll") \
    for (int jj=0;jj<4;jj++){ \
      const int j = (w<<2) + jj; \
      const int rK = (j<<2) + lg; \
      const int cK = ((l15 ^ (rK & 15)) << 3); \
      gl_lds16(kb_ + (size_t)(t0s + rK)*3072 + cK, &Klds[BUF][j*512]); \
      const int rV = (j<<3) + (lane>>3); \
      const int cV = (((lane&7) ^ (lane>>3)) << 3); \
      gl_lds16(vb_ + (size_t)rV*2048 + t0s + cV, &Vlds[BUF][j*512]); \
    } \
  } while(0)

  STAGE(0, 0);
  asm volatile("s_waitcnt vmcnt(0)" ::: "memory");
  __syncthreads();

  char* Pw = (char*)Plds + (w<<11);
  int cur = 0;
  for (int t=0; t<=qhi; ++t){
    if (t < qhi) STAGE(t+1, cur^1);
    const char* Kb = (const char*)&Klds[cur][0];
    const char* Vb = (const char*)&Vlds[cur][0];
    const int t0 = t << 6;
    attn_tile(Kb, Vb, Pw, qfH, oaccH, mH, lH, q0H + (w<<4), t0, t==qhi, l15, lg);
    if (t <= qlo)
      attn_tile(Kb, Vb, Pw, qfL, oaccL, mL, lL, q0L + (w<<4), t0, t==qlo, l15, lg);
    asm volatile("s_waitcnt vmcnt(0)" ::: "memory");
    __syncthreads();
    cur ^= 1;
  }
#undef STAGE

  #pragma unroll
  for (int r=0;r<4;r++){
    const float invH = 1.0f / lH[r];
    const float invL = 1.0f / lL[r];
    u16* opH = aout + (size_t)(b*2048 + q0H + (w<<4) + (lg<<2) + r)*2048 + h*128 + l15;
    u16* opL = aout + (size_t)(b*2048 + q0L + (w<<4) + (lg<<2) + r)*2048 + h*128 + l15;
    #pragma unroll
    for (int d=0;d<8;d++){
      opH[d<<4] = f2bf(oaccH[d][r] * invH);
      opL[d<<4] = f2bf(oaccL[d][r] * invL);
    }
  }
}

extern "C" void kernel_launch(void* const* d_in, const int* in_sizes, int n_in,
                              void* d_out, int out_size, void* d_ws, size_t ws_size,
                              hipStream_t stream) {
  const float* x  = (const float*)d_in[0];
  const float* wq = (const float*)d_in[1];
  const float* wk = (const float*)d_in[2];
  const float* wv = (const float*)d_in[3];
  const float* wo = (const float*)d_in[4];
  const float* qw = (const float*)d_in[5];
  const float* kw = (const float*)d_in[6];
  char* ws = (char*)d_ws;
  u16* xbf   = (u16*)(ws);                 // 16 MB; reused as attn_out
  u16* wqkvT = (u16*)(ws + 16777216);      // 12 MB: [3072][2048] = wqT|wkT|wvT
  u16* woT   = (u16*)(ws + 29360128);      // 8 MB:  [2048][2048]
  u16* qkv   = (u16*)(ws + 37748736);      // 24 MB: [4096][3072] q|k|v
  u16* vT    = (u16*)(ws + 62914560);      // 4 MB:  [8][128][2048]
  float* out = (float*)d_out;

  dim3 tb(32,8);
  cvt_x<<<8192, 256, 0, stream>>>(x, xbf, 2097152);
  transpose_cvt<<<dim3(64,64), tb, 0, stream>>>(wq, wqkvT,             2048, 2048);
  transpose_cvt<<<dim3(16,64), tb, 0, stream>>>(wk, wqkvT + 2048*2048, 2048, 512);
  transpose_cvt<<<dim3(16,64), tb, 0, stream>>>(wv, wqkvT + 2560*2048, 2048, 512);
  transpose_cvt<<<dim3(64,64), tb, 0, stream>>>(wo, woT,               2048, 2048);
  gemm_bt<1><<<768, 256, 0, stream>>>(xbf, wqkvT, qkv, 4096, 3072, 2048, 3072);
  rmsnorm_qk<<<20480, 256, 0, stream>>>(qkv, qw, kw);
  v_transpose<<<dim3(64,4,8), tb, 0, stream>>>(qkv, vT);
  attn_kernel<<<dim3(16,16,2), 256, 0, stream>>>(qkv, vT, xbf);
  gemm_bt<0><<<512, 256, 0, stream>>>(xbf, woT, out, 4096, 2048, 2048, 2048);
}

// Round 3
// 233.468 us; speedup vs baseline: 2.0445x; 1.0894x over previous
//
#include <hip/hip_runtime.h>
#include <hip/hip_bf16.h>
#include <stdint.h>

typedef unsigned short u16;
typedef __attribute__((ext_vector_type(8))) short short8;
typedef __attribute__((ext_vector_type(4))) float f32x4;

__device__ __forceinline__ u16 f2bf(float f){
  union { __hip_bfloat16 h; u16 u; } v; v.h = __float2bfloat16(f); return v.u;
}
__device__ __forceinline__ float bf2f(u16 h){
  union { uint32_t u; float f; } v; v.u = ((uint32_t)h) << 16;
  return v.f;
}
__device__ __forceinline__ f32x4 mfma16(short8 a, short8 b, f32x4 c){
  return __builtin_amdgcn_mfma_f32_16x16x32_bf16(a, b, c, 0, 0, 0);
}
__device__ __forceinline__ void gl_lds16(const u16* g, u16* l){
  __builtin_amdgcn_global_load_lds((const __attribute__((address_space(1))) void*)g,
                                   (__attribute__((address_space(3))) void*)l, 16, 0, 0);
}

// ---------------- f32 -> bf16 convert (x) ----------------
__global__ __launch_bounds__(256) void cvt_x(const float* __restrict__ s,
                                             u16* __restrict__ d, int n4){
  const int i = blockIdx.x*256 + threadIdx.x;
  if (i >= n4) return;
  const float4 v = ((const float4*)s)[i];
  ushort4 pk;
  pk.x = f2bf(v.x); pk.y = f2bf(v.y); pk.z = f2bf(v.z); pk.w = f2bf(v.w);
  ((ushort4*)d)[i] = pk;
}

// ---------------- f32 [R][C] -> bf16 [C][R] transpose ----------------
__global__ __launch_bounds__(256) void transpose_cvt(const float* __restrict__ src,
    u16* __restrict__ dst, int R, int C)
{
  __shared__ float tile[32][33];
  const int tx = threadIdx.x, ty = threadIdx.y;
  const int c0 = blockIdx.x << 5, r0 = blockIdx.y << 5;
  #pragma unroll
  for (int i=0;i<4;i++)
    tile[ty + (i<<3)][tx] = src[(size_t)(r0 + ty + (i<<3))*C + c0 + tx];
  __syncthreads();
  #pragma unroll
  for (int i=0;i<4;i++)
    dst[(size_t)(c0 + ty + (i<<3))*R + r0 + tx] = f2bf(tile[tx][ty + (i<<3)]);
}

// ---------------- V transpose: qkv v-slice [S][128] -> vT [128][S] per (b,kv) ----------------
__global__ __launch_bounds__(256) void v_transpose(const u16* __restrict__ qkv,
    u16* __restrict__ vT)
{
  __shared__ u16 tile[32][33];
  const int tx = threadIdx.x, ty = threadIdx.y;
  const int s0 = blockIdx.x << 5, d0 = blockIdx.y << 5;
  const int bk = blockIdx.z; const int b = bk >> 2, kv = bk & 3;
  const u16* src = qkv + (size_t)b*2048*3072 + 2560 + kv*128;
  #pragma unroll
  for (int i=0;i<4;i++)
    tile[ty + (i<<3)][tx] = src[(size_t)(s0 + ty + (i<<3))*3072 + d0 + tx];
  __syncthreads();
  u16* dst = vT + (size_t)((b<<2)+kv)*128*2048;
  #pragma unroll
  for (int i=0;i<4;i++)
    dst[(size_t)(d0 + ty + (i<<3))*2048 + s0 + tx] = tile[tx][ty + (i<<3)];
}

// ---------------- RMSNorm over each 128-wide head row of q and k ----------------
// q heads additionally scaled by 1/sqrt(128)*log2(e) so attention scores land
// directly in the exp2 domain (softmax uses v_exp_f32 = 2^x natively).
__global__ __launch_bounds__(256) void rmsnorm_qk(u16* __restrict__ qkv,
    const float* __restrict__ qw, const float* __restrict__ kw)
{
  const int lane = threadIdx.x & 63;
  const int rid = blockIdx.x*4 + (threadIdx.x >> 6);   // 0..81919
  const int row = rid / 20;
  const int slot = rid % 20;                            // 0..15 q heads, 16..19 k heads
  u16* p = qkv + (size_t)row*3072 + slot*128 + (lane<<1);
  const u16 r0 = p[0], r1 = p[1];
  const float a = bf2f(r0), c = bf2f(r1);
  float ss = a*a + c*c;
  #pragma unroll
  for (int off=1; off<64; off<<=1) ss += __shfl_xor(ss, off);
  float sc = rsqrtf(ss*(1.0f/128.0f) + 1e-6f);
  if (slot < 16) sc *= 0.1275187952317199f;  // (1/sqrt(128)) * log2(e)
  const float* wp = (slot < 16) ? qw : kw;
  const float w0 = wp[lane<<1], w1 = wp[(lane<<1)+1];
  p[0] = f2bf(a*sc*w0);
  p[1] = f2bf(c*sc*w1);
}

// ---------------- bf16 GEMM: A[M][K] @ BT[N][K]^T -> C[M][ldc] ----------------
template<int CBF16>
__global__ __launch_bounds__(256) void gemm_bt(const u16* __restrict__ A,
    const u16* __restrict__ BT, void* __restrict__ Cp,
    int M, int N, int K, int ldc)
{
  __shared__ u16 As[128*64];
  __shared__ u16 Bs[128*64];
  const int tid = threadIdx.x;
  const int w = tid >> 6, lane = tid & 63;
  const int l15 = lane & 15, lg = lane >> 4;
  const int nbx = N >> 7;
  const int nwg = gridDim.x;
  int bid = blockIdx.x;
  bid = (bid & 7) * (nwg >> 3) + (bid >> 3);   // bijective XCD swizzle (nwg % 8 == 0)
  const int m0 = (bid / nbx) << 7;
  const int n0 = (bid % nbx) << 7;
  const int wm = w >> 1, wn = w & 1;

  f32x4 acc[4][4];
  #pragma unroll
  for (int m=0;m<4;m++)
    #pragma unroll
    for (int n=0;n<4;n++) acc[m][n] = (f32x4){0.f,0.f,0.f,0.f};

  const int rowi = lane >> 3;                 // 0..7 row-within-instr
  const int colS = ((lane & 7) ^ rowi) << 3;  // pre-swizzled source col (elems)

  for (int k0 = 0; k0 < K; k0 += 64) {
    #pragma unroll
    for (int jj=0;jj<4;jj++){
      const int j = (w<<2) + jj;              // 0..15
      const int row = (j<<3) + rowi;          // 0..127
      gl_lds16(A  + (size_t)(m0+row)*K + k0 + colS, As + j*512);
      gl_lds16(BT + (size_t)(n0+row)*K + k0 + colS, Bs + j*512);
    }
    __syncthreads();
    short8 af[4][2], bf[4][2];
    #pragma unroll
    for (int m=0;m<4;m++){
      const int row = (wm<<6) + (m<<4) + l15;
      #pragma unroll
      for (int kk=0;kk<2;kk++){
        const int kb = (kk<<6) + (lg<<4);
        af[m][kk] = *(const short8*)((const char*)As + row*128 + (kb ^ ((row&7)<<4)));
      }
    }
    #pragma unroll
    for (int n=0;n<4;n++){
      const int row = (wn<<6) + (n<<4) + l15;
      #pragma unroll
      for (int kk=0;kk<2;kk++){
        const int kb = (kk<<6) + (lg<<4);
        bf[n][kk] = *(const short8*)((const char*)Bs + row*128 + (kb ^ ((row&7)<<4)));
      }
    }
    #pragma unroll
    for (int kk=0;kk<2;kk++)
      #pragma unroll
      for (int m=0;m<4;m++)
        #pragma unroll
        for (int n=0;n<4;n++)
          acc[m][n] = mfma16(af[m][kk], bf[n][kk], acc[m][n]);
    __syncthreads();
  }

  #pragma unroll
  for (int m=0;m<4;m++){
    #pragma unroll
    for (int n=0;n<4;n++){
      const int col = n0 + (wn<<6) + (n<<4) + l15;
      #pragma unroll
      for (int r=0;r<4;r++){
        const int row = m0 + (wm<<6) + (m<<4) + (lg<<2) + r;
        if (CBF16) ((u16*)Cp)[(size_t)row*ldc + col] = f2bf(acc[m][n][r]);
        else       ((float*)Cp)[(size_t)row*ldc + col] = acc[m][n][r];
      }
    }
  }
}

// ---------------- per-tile attention compute: swapped QK^T, in-reg softmax, PV ----
// mfma(K,Q) gives S^T: lane holds 16 scores (k = nf*16 + lg*4 + r) of q-row l15.
// Row-reduce = in-register tree + 2 shfls (xor 16/32). Defer-max (T13) skips
// the O-rescale when the running max grows by <= 8 (log2 domain).
__device__ __forceinline__ void attn_tile(
    const char* Kb, const char* Vb, char* Pw,
    const short8* qf, f32x4* oacc, float& m_run, float& lsum,
    int rowg, int t0, bool diag, int l15, int lg)
{
  f32x4 sacc[4];
  #pragma unroll
  for (int nf=0;nf<4;nf++) sacc[nf] = (f32x4){0.f,0.f,0.f,0.f};
  #pragma unroll
  for (int kk=0;kk<4;kk++){
    const int kbyte = (kk<<6) + (lg<<4);
    #pragma unroll
    for (int nf=0;nf<4;nf++){
      const int row = (nf<<4) + l15;
      const short8 kv8 = *(const short8*)(Kb + row*256 + (kbyte ^ ((row&15)<<4)));
      sacc[nf] = mfma16(kv8, qf[kk], sacc[nf]);   // swapped: S^T
    }
  }

  float p[16];
  #pragma unroll
  for (int nf=0;nf<4;nf++)
    #pragma unroll
    for (int r=0;r<4;r++){
      float sv = sacc[nf][r];
      if (diag){
        const int colg = t0 + (nf<<4) + (lg<<2) + r;
        if (colg > rowg) sv = -__builtin_inff();
      }
      p[(nf<<2)+r] = sv;
    }

  float t8[8];
  #pragma unroll
  for (int i=0;i<8;i++) t8[i] = fmaxf(p[i], p[i+8]);
  #pragma unroll
  for (int i=0;i<4;i++) t8[i] = fmaxf(t8[i], t8[i+4]);
  float mx = fmaxf(fmaxf(t8[0],t8[1]), fmaxf(t8[2],t8[3]));
  mx = fmaxf(mx, __shfl_xor(mx, 16));
  mx = fmaxf(mx, __shfl_xor(mx, 32));

  const bool noskip = !__all(mx - m_run <= 8.0f);
  const float mnew = noskip ? fmaxf(m_run, mx) : m_run;

  float s8[8];
  #pragma unroll
  for (int i=0;i<8;i++){
    p[i]   = __builtin_amdgcn_exp2f(p[i]   - mnew);
    p[i+8] = __builtin_amdgcn_exp2f(p[i+8] - mnew);
    s8[i] = p[i] + p[i+8];
  }
  #pragma unroll
  for (int i=0;i<4;i++) s8[i] += s8[i+4];
  float rs = (s8[0]+s8[1]) + (s8[2]+s8[3]);
  rs += __shfl_xor(rs, 16);
  rs += __shfl_xor(rs, 32);

  if (noskip){
    const float corr = __builtin_amdgcn_exp2f(m_run - mnew);
    m_run = mnew;
    lsum = lsum*corr + rs;
    #pragma unroll
    for (int d=0;d<8;d++)
      #pragma unroll
      for (int r=0;r<4;r++)
        oacc[d][r] *= corr;
  } else {
    lsum += rs;
  }

  // P -> per-wave LDS: 4x ds_write_b64, swizzled by q-row
  #pragma unroll
  for (int nf=0;nf<4;nf++){
    uint2 v;
    v.x = (uint32_t)f2bf(p[(nf<<2)+0]) | ((uint32_t)f2bf(p[(nf<<2)+1]) << 16);
    v.y = (uint32_t)f2bf(p[(nf<<2)+2]) | ((uint32_t)f2bf(p[(nf<<2)+3]) << 16);
    *(uint2*)(Pw + l15*128 + (((nf<<5) + (lg<<3)) ^ ((l15&7)<<4))) = v;
  }
  asm volatile("s_waitcnt lgkmcnt(0)" ::: "memory");
  __builtin_amdgcn_sched_barrier(0);

  // O += P V
  #pragma unroll
  for (int kk=0;kk<2;kk++){
    const int kbyte = (kk<<6) + (lg<<4);
    const short8 pa = *(const short8*)(Pw + l15*128 + (kbyte ^ ((l15&7)<<4)));
    #pragma unroll
    for (int d=0;d<8;d++){
      const int row = (d<<4) + l15;
      const short8 vv = *(const short8*)(Vb + row*128 + (kbyte ^ ((row&7)<<4)));
      oacc[d] = mfma16(pa, vv, oacc[d]);
    }
  }
}

// ---------------- causal GQA flash attention, triangle-paired + double-buffered ----------------
__global__ __launch_bounds__(256, 2) void attn_kernel(const u16* __restrict__ qkv,
    const u16* __restrict__ vT, u16* __restrict__ aout)
{
  __shared__ u16 Klds[2][64*128];
  __shared__ u16 Vlds[2][128*64];
  __shared__ u16 Plds[4*16*64];
  const int tid = threadIdx.x;
  const int w = tid >> 6, lane = tid & 63;
  const int l15 = lane & 15, lg = lane >> 4;
  const int p = blockIdx.x;                 // 0..15
  const int h = blockIdx.y, b = blockIdx.z;
  const int kvh = h >> 2;
  const int qlo = p, qhi = 31 - p;
  const int q0L = qlo << 6, q0H = qhi << 6;

  const u16* qkvb = qkv + (size_t)b*2048*3072;
  short8 qfL[4], qfH[4];
  {
    const u16* qpL = qkvb + (size_t)(q0L + (w<<4) + l15)*3072 + h*128 + lg*8;
    const u16* qpH = qkvb + (size_t)(q0H + (w<<4) + l15)*3072 + h*128 + lg*8;
    #pragma unroll
    for (int kk=0;kk<4;kk++){ qfL[kk] = *(const short8*)(qpL + kk*32);
                              qfH[kk] = *(const short8*)(qpH + kk*32); }
  }
  f32x4 oaccL[8], oaccH[8];
  #pragma unroll
  for (int d=0;d<8;d++){ oaccL[d] = (f32x4){0.f,0.f,0.f,0.f};
                         oaccH[d] = (f32x4){0.f,0.f,0.f,0.f}; }
  float mL = -__builtin_inff(), lL = 0.f;
  float mH = -__builtin_inff(), lH = 0.f;

  const u16* kb_ = qkvb + 2048 + kvh*128;
  const u16* vb_ = vT + (size_t)((b<<2)+kvh)*128*2048;

#define STAGE(T, BUF) do { \
    const int t0s = (T) << 6; \
    _Pragma("unroll") \
    for (int jj=0;jj<4;jj++){ \
      const int j = (w<<2) + jj; \
      const int rK = (j<<2) + lg; \
      const int cK = ((l15 ^ (rK & 15)) << 3); \
      gl_lds16(kb_ + (size_t)(t0s + rK)*3072 + cK, &Klds[BUF][j*512]); \
      const int rV = (j<<3) + (lane>>3); \
      const int cV = (((lane&7) ^ (lane>>3)) << 3); \
      gl_lds16(vb_ + (size_t)rV*2048 + t0s + cV, &Vlds[BUF][j*512]); \
    } \
  } while(0)

  STAGE(0, 0);
  asm volatile("s_waitcnt vmcnt(0)" ::: "memory");
  __syncthreads();

  char* Pw = (char*)Plds + (w<<11);
  int cur = 0;
  for (int t=0; t<=qhi; ++t){
    if (t < qhi) STAGE(t+1, cur^1);
    const char* Kb = (const char*)&Klds[cur][0];
    const char* Vb = (const char*)&Vlds[cur][0];
    const int t0 = t << 6;
    attn_tile(Kb, Vb, Pw, qfH, oaccH, mH, lH, q0H + (w<<4) + l15, t0, t==qhi, l15, lg);
    if (t <= qlo)
      attn_tile(Kb, Vb, Pw, qfL, oaccL, mL, lL, q0L + (w<<4) + l15, t0, t==qlo, l15, lg);
    asm volatile("s_waitcnt vmcnt(0)" ::: "memory");
    __syncthreads();
    cur ^= 1;
  }
#undef STAGE

  #pragma unroll
  for (int r=0;r<4;r++){
    u16* opH = aout + (size_t)(b*2048 + q0H + (w<<4) + (lg<<2) + r)*2048 + h*128 + l15;
    u16* opL = aout + (size_t)(b*2048 + q0L + (w<<4) + (lg<<2) + r)*2048 + h*128 + l15;
    const float invH = 1.0f / __shfl(lH, ((lg<<2)+r) + (lane & 48));
    const float invL = 1.0f / __shfl(lL, ((lg<<2)+r) + (lane & 48));
    #pragma unroll
    for (int d=0;d<8;d++){
      opH[d<<4] = f2bf(oaccH[d][r] * invH);
      opL[d<<4] = f2bf(oaccL[d][r] * invL);
    }
  }
}

extern "C" void kernel_launch(void* const* d_in, const int* in_sizes, int n_in,
                              void* d_out, int out_size, void* d_ws, size_t ws_size,
                              hipStream_t stream) {
  const float* x  = (const float*)d_in[0];
  const float* wq = (const float*)d_in[1];
  const float* wk = (const float*)d_in[2];
  const float* wv = (const float*)d_in[3];
  const float* wo = (const float*)d_in[4];
  const float* qw = (const float*)d_in[5];
  const float* kw = (const float*)d_in[6];
  char* ws = (char*)d_ws;
  u16* xbf   = (u16*)(ws);                 // 16 MB; reused as attn_out
  u16* wqkvT = (u16*)(ws + 16777216);      // 12 MB: [3072][2048] = wqT|wkT|wvT
  u16* woT   = (u16*)(ws + 29360128);      // 8 MB:  [2048][2048]
  u16* qkv   = (u16*)(ws + 37748736);      // 24 MB: [4096][3072] q|k|v
  u16* vT    = (u16*)(ws + 62914560);      // 4 MB:  [8][128][2048]
  float* out = (float*)d_out;

  dim3 tb(32,8);
  cvt_x<<<8192, 256, 0, stream>>>(x, xbf, 2097152);
  transpose_cvt<<<dim3(64,64), tb, 0, stream>>>(wq, wqkvT,             2048, 2048);
  transpose_cvt<<<dim3(16,64), tb, 0, stream>>>(wk, wqkvT + 2048*2048, 2048, 512);
  transpose_cvt<<<dim3(16,64), tb, 0, stream>>>(wv, wqkvT + 2560*2048, 2048, 512);
  transpose_cvt<<<dim3(64,64), tb, 0, stream>>>(wo, woT,               2048, 2048);
  gemm_bt<1><<<768, 256, 0, stream>>>(xbf, wqkvT, qkv, 4096, 3072, 2048, 3072);
  rmsnorm_qk<<<20480, 256, 0, stream>>>(qkv, qw, kw);
  v_transpose<<<dim3(64,4,8), tb, 0, stream>>>(qkv, vT);
  attn_kernel<<<dim3(16,16,2), 256, 0, stream>>>(qkv, vT, xbf);
  gemm_bt<0><<<512, 256, 0, stream>>>(xbf, woT, out, 4096, 2048, 2048, 2048);
}